// Round 20
// baseline (271.475 us; speedup 1.0000x reference)
//
#include <hip/hip_runtime.h>
#include <hip/hip_bf16.h>

#define T_DIM 4096
#define B_DIM 32
#define I_DIM 512
#define O_DIM 512
#define M_DIM (T_DIM * B_DIM)   // 131072
#define PARAM 0.1f
#define ISCALE 1.1111112f       // 1/(1-p)

#define BM 256                  // 8 t's per block
#define BN 128
#define BK 64
#define NK (I_DIM / BK)         // 8

typedef __attribute__((ext_vector_type(8))) short bf16x8;
typedef __attribute__((ext_vector_type(4))) float f32x4;

__device__ __forceinline__ unsigned short f2bf(float f) {
    union { __hip_bfloat16 b; unsigned short u; } cv;
    cv.b = __float2bfloat16(f);
    return cv.u;
}

// --- W fp32 -> bf16 (0.5 MB, ws offset 0) ---
__global__ __launch_bounds__(256) void wcvt_kernel(const float* __restrict__ W,
                                                   unsigned short* __restrict__ Wb) {
    const int i = (blockIdx.x * 256 + threadIdx.x) * 4;
    f32x4 v = *(const f32x4*)(W + i);
    ushort4 o;
    o.x = f2bf(v[0]); o.y = f2bf(v[1]); o.z = f2bf(v[2]); o.w = f2bf(v[3]);
    *(ushort4*)(Wb + i) = o;
}

// --- FUSED EMA+GEMM: Y[t] = EMA(X)[t] @ W^T + s[t]*bias.
// Each block: 256 rows (= 8 t's x 32 b) x 128 W-cols. Per K-step each thread
// owns one (b, k-quad) EMA chain: 16 strided float4 X loads (8 warm-up t's,
// p^8=1e-8 truncation; 8 in-window) into a NAMED xr[16] register array issued
// BEFORE the MFMA phase (latency hides under compute), then 16 FMA4 + cvt +
// 8 swizzled ds_write into the double-buffered A tile. B tile via pre-swizzled
// global_load_lds. One barrier per K-step (2-phase). Swapped-operand MFMA ->
// Y^T frags -> float4 epilogue. This removes the separate xema kernel (~80us
// serial) and the Xv round-trip; the EMA work lands in the GEMM's idle issue
// slots (all pipes were <20% busy). XCD map: bn-quad of one mt adjacent on one
// XCD -> warm-up re-reads L2-dedup'd. ---
__global__ __launch_bounds__(512, 2) void fused_kernel(const float* __restrict__ X,
                                                       const unsigned short* __restrict__ Wb,
                                                       const float* __restrict__ bias,
                                                       float* __restrict__ Y) {
    __shared__ __align__(16) short As[2][BM * BK];   // 32 KB x2
    __shared__ __align__(16) short Bs[2][BN * BK];   // 16 KB x2

    const int tid  = threadIdx.x;
    const int lane = tid & 63;
    const int wave = tid >> 6;      // 0..7
    const int wm   = wave >> 2;     // 0..1 (128-row half)
    const int wn   = wave & 3;      // 0..3 (32-col quarter)

    // 2048 blocks: xcd = bid&7; bn (0..3) fastest within an XCD chunk, then mt.
    const int bid = blockIdx.x;
    const int swz = (bid & 7) * 256 + (bid >> 3);
    const int bn  = swz & 3;
    const int mt  = swz >> 2;                   // 0..511
    const int row0 = mt * BM;
    const int col0 = bn * BN;
    const int t0   = mt * 8;                    // first t of this block

    // --- B staging (pre-swizzled source, involution c^(r&7)) ---
    const int cs = (tid & 7) ^ ((tid >> 3) & 7);
    const unsigned short* bSrc = Wb + (size_t)(col0 + (tid >> 3)) * 512 + cs * 8;

    #define STAGE_B(d, kt)                                                            \
        do {                                                                          \
            _Pragma("unroll")                                                         \
            for (int s_ = 0; s_ < 2; ++s_)                                            \
                __builtin_amdgcn_global_load_lds(                                     \
                    (const __attribute__((address_space(1))) unsigned int*)(bSrc + (size_t)s_ * 64 * 512 + (kt) * 64), \
                    (__attribute__((address_space(3))) unsigned int*)(&Bs[d][0] + (s_ * 512 + tid) * 8),              \
                    16, 0, 0);                                                        \
        } while (0)

    // --- EMA chain geometry: thread owns (b = tid>>4, k-quad kq = tid&15). ---
    const int bb = tid >> 4;     // 0..31
    const int kq = tid & 15;     // k = kq*4 within the 64-wide slice
    const float* xBase = X + (size_t)bb * 512 + kq * 4;
    // A ds_write: row r = tl*32+bb -> r&7 = bb&7 (thread-constant swizzle)
    const int aw = (((kq >> 1) ^ (bb & 7)) << 4) + ((kq & 1) << 3);

    f32x4 xr[16];   // named register array, static indices only (rule #20)

    #define XLOAD(ks_)                                                                \
        do {                                                                          \
            const float* xp = xBase + (size_t)(ks_) * 64;                             \
            if (t0 >= 8) {                                                            \
                _Pragma("unroll")                                                     \
                for (int j_ = 0; j_ < 16; ++j_)                                       \
                    xr[j_] = *(const f32x4*)(xp + (size_t)(t0 - 8 + j_) * 16384);     \
            } else {                                                                  \
                _Pragma("unroll")                                                     \
                for (int j_ = 0; j_ < 16; ++j_) {                                     \
                    const int t_ = t0 - 8 + j_;                                       \
                    if (t_ >= 0) xr[j_] = *(const f32x4*)(xp + (size_t)t_ * 16384);   \
                    else         xr[j_] = (f32x4){0.f, 0.f, 0.f, 0.f};                \
                }                                                                     \
            }                                                                         \
        } while (0)

    #define EMA_WRITE(d)                                                              \
        do {                                                                          \
            f32x4 v_ = xr[0];                                                         \
            _Pragma("unroll")                                                         \
            for (int j_ = 1; j_ < 8; ++j_) v_ = PARAM * v_ + xr[j_];                  \
            _Pragma("unroll")                                                         \
            for (int tl = 0; tl < 8; ++tl) {                                          \
                v_ = PARAM * v_ + xr[8 + tl];                                         \
                ushort4 pk_;                                                          \
                pk_.x = f2bf(v_[0]); pk_.y = f2bf(v_[1]);                             \
                pk_.z = f2bf(v_[2]); pk_.w = f2bf(v_[3]);                             \
                *(ushort4*)((char*)&As[d][0] + (tl * 32 + bb) * 128 + aw) = pk_;      \
            }                                                                         \
        } while (0)

    f32x4 acc[8][2] = {};   // [mf][nf], swapped-operand: reg j = 4 consecutive Y-cols

    #define COMPUTE(d)                                                                \
        do {                                                                          \
            _Pragma("unroll")                                                         \
            for (int kk = 0; kk < 2; ++kk) {                                          \
                const int cc = kk * 4 + (lane >> 4);                                  \
                bf16x8 a_[8], b_[2];                                                  \
                _Pragma("unroll")                                                     \
                for (int mf = 0; mf < 8; ++mf) {                                      \
                    const int r = wm * 128 + mf * 16 + (lane & 15);                   \
                    a_[mf] = *(const bf16x8*)((const char*)&As[d][0] + r * 128 + ((cc ^ (r & 7)) << 4)); \
                }                                                                     \
                _Pragma("unroll")                                                     \
                for (int nf = 0; nf < 2; ++nf) {                                      \
                    const int r = wn * 32 + nf * 16 + (lane & 15);                    \
                    b_[nf] = *(const bf16x8*)((const char*)&Bs[d][0] + r * 128 + ((cc ^ (r & 7)) << 4)); \
                }                                                                     \
                _Pragma("unroll")                                                     \
                for (int mf = 0; mf < 8; ++mf)                                        \
                    _Pragma("unroll")                                                 \
                    for (int nf = 0; nf < 2; ++nf)                                    \
                        acc[mf][nf] = __builtin_amdgcn_mfma_f32_16x16x32_bf16(        \
                            b_[nf], a_[mf], acc[mf][nf], 0, 0, 0);                    \
            }                                                                         \
        } while (0)

    // Prologue: build tile 0 (A via EMA, B via gload_lds).
    STAGE_B(0, 0);
    XLOAD(0);
    EMA_WRITE(0);
    __syncthreads();

    #pragma unroll
    for (int ks = 0; ks < NK; ++ks) {
        const int cur = ks & 1;
        if (ks < NK - 1) {
            STAGE_B(cur ^ 1, ks + 1);   // async into other buffer
            XLOAD(ks + 1);              // X loads fly under the MFMAs below
        }
        COMPUTE(cur);
        if (ks < NK - 1)
            EMA_WRITE(cur ^ 1);         // VALU on landed loads + ds_write
        __syncthreads();                // drains B gloads + A ds_writes
    }

    // Epilogue: Y = acc + s[t]*bias, float4 stores (Y^T frag: reg j = 4 cols).
    // t = t0 + wm*4 + (mf>>1).
    float sc4[4];
    #pragma unroll
    for (int tt = 0; tt < 4; ++tt) {
        const int t_ = t0 + wm * 4 + tt;
        sc4[tt] = (1.0f - __expf(-2.3025851f * (float)(t_ + 1))) * ISCALE;
    }
    f32x4 bvv[2];
    #pragma unroll
    for (int nf = 0; nf < 2; ++nf)
        bvv[nf] = *(const f32x4*)(bias + col0 + wn * 32 + nf * 16 + ((lane >> 4) << 2));

    #pragma unroll
    for (int mf = 0; mf < 8; ++mf) {
        const int grow = row0 + wm * 128 + mf * 16 + (lane & 15);
        const float sc = sc4[mf >> 1];
        #pragma unroll
        for (int nf = 0; nf < 2; ++nf) {
            const int gcol = col0 + wn * 32 + nf * 16 + ((lane >> 4) << 2);
            f32x4 out;
            #pragma unroll
            for (int e = 0; e < 4; ++e) out[e] = acc[mf][nf][e] + sc * bvv[nf][e];
            *(f32x4*)(Y + (size_t)grow * O_DIM + gcol) = out;
        }
    }
    #undef STAGE_B
    #undef XLOAD
    #undef EMA_WRITE
    #undef COMPUTE
}

extern "C" void kernel_launch(void* const* d_in, const int* in_sizes, int n_in,
                              void* d_out, int out_size, void* d_ws, size_t ws_size,
                              hipStream_t stream) {
    const float* X    = (const float*)d_in[0];
    const float* W    = (const float*)d_in[1];
    const float* bias = (const float*)d_in[2];
    float* Y = (float*)d_out;
    unsigned short* Wb = (unsigned short*)d_ws;   // 512 KB

    wcvt_kernel<<<dim3(O_DIM * I_DIM / (256 * 4)), dim3(256), 0, stream>>>(W, Wb);
    fused_kernel<<<dim3((M_DIM / BM) * (O_DIM / BN)), dim3(512), 0, stream>>>(X, Wb, bias, Y);
}

// Round 21
// 226.758 us; speedup vs baseline: 1.1972x; 1.1972x over previous
//
#include <hip/hip_runtime.h>
#include <hip/hip_bf16.h>

#define T_DIM 4096
#define B_DIM 32
#define I_DIM 512
#define O_DIM 512
#define M_DIM (T_DIM * B_DIM)   // 131072
#define PARAM 0.1f
#define ISCALE 1.1111112f       // 1/(1-p)

#define STRIP 32
#define TAPS 8                  // p^8 = 1e-8 << bf16 eps

#define BM 128
#define BN 128
#define BK 64
#define NK (I_DIM / BK)         // 8

typedef __attribute__((ext_vector_type(8))) short bf16x8;
typedef __attribute__((ext_vector_type(4))) float f32x4;

__device__ __forceinline__ unsigned short f2bf(float f) {
    union { __hip_bfloat16 b; unsigned short u; } cv;
    cv.b = __float2bfloat16(f);
    return cv.u;
}

// --- EMA over raw X (linearity: EMA(XW+b) = EMA(X)W + s[t]*bias). Strip-
// parallel, TAPS warm-up reads raw X; bf16 output compacted into d_ws.
// Blocks 0..255 ALSO convert W fp32->bf16 (folded wcvt: xema fully completes
// before gemm on the same stream, so Wb is ready when gemm starts). ---
__global__ __launch_bounds__(256) void xema_kernel(const float* __restrict__ X,
                                                   const float* __restrict__ W,
                                                   unsigned short* __restrict__ Xv,
                                                   unsigned short* __restrict__ Wb) {
    // folded W conversion: 256 blocks x 256 thr x 4 floats = 512*512
    if (blockIdx.x < 256) {
        const int i = (blockIdx.x * 256 + threadIdx.x) * 4;
        f32x4 v = *(const f32x4*)(W + i);
        ushort4 o;
        o.x = f2bf(v[0]); o.y = f2bf(v[1]); o.z = f2bf(v[2]); o.w = f2bf(v[3]);
        *(ushort4*)(Wb + i) = o;
    }

    const int s   = blockIdx.x >> 4;                 // strip 0..127
    const int blk = blockIdx.x & 15;
    const int col = (blk * 256 + threadIdx.x) * 4;
    const int t0  = s * STRIP;
    const int b   = col >> 9;
    const int o   = col & 511;

    const float* xin = X + (size_t)t0 * 16384 + col;
    unsigned short* xout = Xv + (size_t)(t0 * 32 + b) * 512 + o;

    f32x4 v = {0.f, 0.f, 0.f, 0.f};
    if (s > 0) {
        const float* w = xin - (size_t)TAPS * 16384;
        #pragma unroll
        for (int j = 0; j < TAPS; ++j)
            v = PARAM * v + *(const f32x4*)(w + (size_t)j * 16384);
    }

    f32x4 bufA[4], bufB[4];
    #pragma unroll
    for (int j = 0; j < 4; ++j) bufA[j] = *(const f32x4*)(xin + (size_t)j * 16384);

    #pragma unroll
    for (int i = 0; i < STRIP; i += 8) {
        #pragma unroll
        for (int j = 0; j < 4; ++j)
            bufB[j] = *(const f32x4*)(xin + (size_t)(i + 4 + j) * 16384);
        #pragma unroll
        for (int j = 0; j < 4; ++j) {
            v = PARAM * v + bufA[j];
            ushort4 pk; pk.x = f2bf(v[0]); pk.y = f2bf(v[1]); pk.z = f2bf(v[2]); pk.w = f2bf(v[3]);
            *(ushort4*)(xout + (size_t)(i + j) * 16384) = pk;
        }
        if (i + 8 < STRIP) {
            #pragma unroll
            for (int j = 0; j < 4; ++j)
                bufA[j] = *(const f32x4*)(xin + (size_t)(i + 8 + j) * 16384);
        }
        #pragma unroll
        for (int j = 0; j < 4; ++j) {
            v = PARAM * v + bufB[j];
            ushort4 pk; pk.x = f2bf(v[0]); pk.y = f2bf(v[1]); pk.z = f2bf(v[2]); pk.w = f2bf(v[3]);
            *(ushort4*)(xout + (size_t)(i + 4 + j) * 16384) = pk;
        }
    }
}

// --- GEMM: best-measured structure (R13/R18). m97 replica: 256 thr / 4 waves,
// 128x128 tile, BK=64, wave-tile 64x64, single-buffer 32KB LDS -> 4 blocks/CU;
// pre-swizzled gload_lds staging (involution c^(r&7)); conflict-free swizzled
// ds_read; swapped-operand MFMA -> Y^T frags -> float4 epilogue; entry stagger
// (neutral-measured, harmless). Latency-bound plateau for NK=8 at ~145us across
// 9 schedule variants — structural for this shape at HIP source level. ---
__global__ __launch_bounds__(256, 4) void gemm_kernel(const unsigned short* __restrict__ Xv,
                                                      const unsigned short* __restrict__ Wb,
                                                      const float* __restrict__ bias,
                                                      float* __restrict__ Y) {
    __shared__ __align__(16) short As[BM * BK];   // 16 KB
    __shared__ __align__(16) short Bs[BN * BK];   // 16 KB

    switch ((blockIdx.x >> 8) & 3) {
        case 1: __builtin_amdgcn_s_sleep(8);  break;
        case 2: __builtin_amdgcn_s_sleep(16); break;
        case 3: __builtin_amdgcn_s_sleep(24); break;
        default: break;
    }

    const int tid  = threadIdx.x;
    const int lane = tid & 63;
    const int wave = tid >> 6;        // 0..3
    const int wm   = wave >> 1;       // 0..1
    const int wn   = wave & 1;        // 0..1

    // 4096 blocks: xcd = bid&7; all 4 bn of one mt adjacent per XCD -> A panel
    // HBM-fetched once, L2-served 4x; W (512KB) stays L2-hot.
    const int bid = blockIdx.x;
    const int j   = bid >> 3;                     // 0..511
    const int bn  = j & 3;
    const int mt  = (bid & 7) * 128 + (j >> 2);   // 0..1023
    const int row0 = mt * BM;
    const int col0 = bn * BN;

    const int cs = (tid & 7) ^ ((tid >> 3) & 7);
    const unsigned short* aSrc = Xv + (size_t)(row0 + (tid >> 3)) * 512 + cs * 8;
    const unsigned short* bSrc = Wb + (size_t)(col0 + (tid >> 3)) * 512 + cs * 8;

    f32x4 acc[4][4] = {};   // [mf][nf], swapped-operand: reg j = 4 consecutive Y-cols

    for (int ks = 0; ks < NK; ++ks) {
        const int k0 = ks * BK;
        #pragma unroll
        for (int s_ = 0; s_ < 4; ++s_)
            __builtin_amdgcn_global_load_lds(
                (const __attribute__((address_space(1))) unsigned int*)(aSrc + (size_t)s_ * 32 * 512 + k0),
                (__attribute__((address_space(3))) unsigned int*)(As + (s_ * 256 + tid) * 8),
                16, 0, 0);
        #pragma unroll
        for (int s_ = 0; s_ < 4; ++s_)
            __builtin_amdgcn_global_load_lds(
                (const __attribute__((address_space(1))) unsigned int*)(bSrc + (size_t)s_ * 32 * 512 + k0),
                (__attribute__((address_space(3))) unsigned int*)(Bs + (s_ * 256 + tid) * 8),
                16, 0, 0);
        __syncthreads();

        #pragma unroll
        for (int kk = 0; kk < 2; ++kk) {
            const int cc = kk * 4 + (lane >> 4);
            bf16x8 a_[4], b_[4];
            #pragma unroll
            for (int mf = 0; mf < 4; ++mf) {
                const int r = wm * 64 + mf * 16 + (lane & 15);
                a_[mf] = *(const bf16x8*)((const char*)As + r * 128 + ((cc ^ (r & 7)) << 4));
            }
            #pragma unroll
            for (int nf = 0; nf < 4; ++nf) {
                const int r = wn * 64 + nf * 16 + (lane & 15);
                b_[nf] = *(const bf16x8*)((const char*)Bs + r * 128 + ((cc ^ (r & 7)) << 4));
            }
            #pragma unroll
            for (int mf = 0; mf < 4; ++mf)
                #pragma unroll
                for (int nf = 0; nf < 4; ++nf)
                    acc[mf][nf] = __builtin_amdgcn_mfma_f32_16x16x32_bf16(
                        b_[nf], a_[mf], acc[mf][nf], 0, 0, 0);   // swapped -> Y^T frag
        }
        __syncthreads();
    }

    // Epilogue: Y = acc + s[t]*bias, float4 stores (Y^T frag: reg j = 4 cols).
    float sc4[2];
    #pragma unroll
    for (int tt = 0; tt < 2; ++tt) {
        const int t_ = ((row0 + wm * 64) >> 5) + tt;
        sc4[tt] = (1.0f - __expf(-2.3025851f * (float)(t_ + 1))) * ISCALE;
    }
    f32x4 bvv[4];
    #pragma unroll
    for (int nf = 0; nf < 4; ++nf)
        bvv[nf] = *(const f32x4*)(bias + col0 + wn * 64 + nf * 16 + ((lane >> 4) << 2));

    #pragma unroll
    for (int mf = 0; mf < 4; ++mf) {
        const int grow = row0 + wm * 64 + mf * 16 + (lane & 15);
        const float sc = sc4[mf >> 1];
        #pragma unroll
        for (int nf = 0; nf < 4; ++nf) {
            const int gcol = col0 + wn * 64 + nf * 16 + ((lane >> 4) << 2);
            f32x4 out;
            #pragma unroll
            for (int e = 0; e < 4; ++e) out[e] = acc[mf][nf][e] + sc * bvv[nf][e];
            *(f32x4*)(Y + (size_t)grow * O_DIM + gcol) = out;
        }
    }
}

extern "C" void kernel_launch(void* const* d_in, const int* in_sizes, int n_in,
                              void* d_out, int out_size, void* d_ws, size_t ws_size,
                              hipStream_t stream) {
    const float* X    = (const float*)d_in[0];
    const float* W    = (const float*)d_in[1];
    const float* bias = (const float*)d_in[2];
    float* Y = (float*)d_out;
    unsigned short* Wb = (unsigned short*)d_ws;                       // 512 KB
    unsigned short* Xv = (unsigned short*)((char*)d_ws + (1 << 20));  // 134 MB

    xema_kernel<<<dim3((T_DIM / STRIP) * 16), dim3(256), 0, stream>>>(X, W, Xv, Wb);
    gemm_kernel<<<dim3((M_DIM / BM) * (O_DIM / BN)), dim3(256), 0, stream>>>(Xv, Wb, bias, Y);
}